// Round 2
// baseline (901.574 us; speedup 1.0000x reference)
//
#include <hip/hip_runtime.h>
#include <math.h>

#define BB    8
#define NQ_   2048
#define NK_   2048
#define D_    64
#define V_    128
#define EPSF  1e-7f

// ---------------------------------------------------------------------------
// Kernel 1: Poincare distances -> scores -> softmax -> attention weights.
// 256 threads = 4 waves; each wave owns 2 q rows (persistent in registers).
// Two passes over K tiles (recompute) so no score storage is needed:
//   pass 1: l = sum(exp(s)) per row (fp32, safe: s in [-35,0])
//   pass 2: w = exp(s) / l, coalesced write.
// ---------------------------------------------------------------------------
#define K1_QT 8
#define K1_KT 64

__global__ __launch_bounds__(256, 2)
void k_scores_softmax(const float* __restrict__ Q,
                      const float* __restrict__ Kp,
                      float* __restrict__ attnW)
{
    __shared__ float sK[K1_KT][D_ + 4];   // +4 pad: conflict-free b128 reads

    const int t  = threadIdx.x;
    const int qg = t >> 6;                // wave id 0..3
    const int tx = t & 63;                // lane
    const int b  = blockIdx.y;
    const int qbase = blockIdx.x * K1_QT;
    const int q0l = qg * 2, q1l = q0l + 1;

    // persistent q rows in registers (wave-uniform loads -> broadcast)
    const float4* Q4 = (const float4*)(Q + ((size_t)b * NQ_ + qbase) * D_);
    float4 qr0[16], qr1[16];
#pragma unroll
    for (int i = 0; i < 16; ++i) { qr0[i] = Q4[q0l*16 + i]; qr1[i] = Q4[q1l*16 + i]; }

    float x2_0 = 0.f, x2_1 = 0.f;
#pragma unroll
    for (int i = 0; i < 16; ++i) {
        x2_0 = fmaf(qr0[i].x,qr0[i].x,x2_0); x2_0 = fmaf(qr0[i].y,qr0[i].y,x2_0);
        x2_0 = fmaf(qr0[i].z,qr0[i].z,x2_0); x2_0 = fmaf(qr0[i].w,qr0[i].w,x2_0);
        x2_1 = fmaf(qr1[i].x,qr1[i].x,x2_1); x2_1 = fmaf(qr1[i].y,qr1[i].y,x2_1);
        x2_1 = fmaf(qr1[i].z,qr1[i].z,x2_1); x2_1 = fmaf(qr1[i].w,qr1[i].w,x2_1);
    }
    const float px0 = 1.f - x2_0, px1 = 1.f - x2_1;

    const float4* K4 = (const float4*)(Kp + (size_t)b * NK_ * D_);

    auto stage = [&](int kt) {
        __syncthreads();                  // protect previous tile's readers
#pragma unroll
        for (int j = 0; j < 4; ++j) {     // 64 rows x 16 float4 = 1024 f4
            int idx = t + j * 256;
            int row = idx >> 4, c = idx & 15;
            *(float4*)&sK[row][c*4] = K4[(kt + row)*16 + c];
        }
        __syncthreads();
    };

    // scores for this lane's k row (= kt + tx) against both q rows
    auto tile_scores = [&](float& s0, float& s1) {
        float d0 = 0.f, d1 = 0.f, y2 = 0.f;
#pragma unroll
        for (int i = 0; i < 16; ++i) {
            float4 kv = *(const float4*)&sK[tx][i*4];
            d0 = fmaf(qr0[i].x,kv.x,d0); d0 = fmaf(qr0[i].y,kv.y,d0);
            d0 = fmaf(qr0[i].z,kv.z,d0); d0 = fmaf(qr0[i].w,kv.w,d0);
            d1 = fmaf(qr1[i].x,kv.x,d1); d1 = fmaf(qr1[i].y,kv.y,d1);
            d1 = fmaf(qr1[i].z,kv.z,d1); d1 = fmaf(qr1[i].w,kv.w,d1);
            y2 = fmaf(kv.x,kv.x,y2);     y2 = fmaf(kv.y,kv.y,y2);
            y2 = fmaf(kv.z,kv.z,y2);     y2 = fmaf(kv.w,kv.w,y2);
        }
        const float py = 1.f - y2;
        {
            float sq   = fmaxf(x2_0 + y2 - 2.f*d0, 0.f);
            float dn   = fmaxf(px0 * py, EPSF);
            float tt   = fmaxf(2.f * sq * __builtin_amdgcn_rcpf(dn), EPSF);
            float dist = log1pf(tt + sqrtf(tt*(tt + 2.f)));   // arccosh(1+tt)
            s0 = -dist * dist;
        }
        {
            float sq   = fmaxf(x2_1 + y2 - 2.f*d1, 0.f);
            float dn   = fmaxf(px1 * py, EPSF);
            float tt   = fmaxf(2.f * sq * __builtin_amdgcn_rcpf(dn), EPSF);
            float dist = log1pf(tt + sqrtf(tt*(tt + 2.f)));
            s1 = -dist * dist;
        }
    };

    // ---- pass 1: row denominators
    float l0 = 0.f, l1 = 0.f;
    for (int kt = 0; kt < NK_; kt += K1_KT) {
        stage(kt);
        float s0, s1; tile_scores(s0, s1);
        l0 += __expf(s0);
        l1 += __expf(s1);
    }
#pragma unroll
    for (int off = 32; off; off >>= 1) {
        l0 += __shfl_xor(l0, off);
        l1 += __shfl_xor(l1, off);
    }
    const float r0 = __builtin_amdgcn_rcpf(l0);
    const float r1 = __builtin_amdgcn_rcpf(l1);

    // ---- pass 2: recompute scores, write normalized weights (coalesced)
    float* W0 = attnW + ((size_t)b * NQ_ + qbase + q0l) * NK_;
    float* W1 = W0 + NK_;
    for (int kt = 0; kt < NK_; kt += K1_KT) {
        stage(kt);
        float s0, s1; tile_scores(s0, s1);
        W0[kt + tx] = __expf(s0) * r0;
        W1[kt + tx] = __expf(s1) * r1;
    }
}

// ---------------------------------------------------------------------------
// Kernel 3: O = W @ V   (per batch: 2048x128 = 2048x2048 * 2048x128), fp32.
// Block tile 128q x 64v, k-tile 32; thread tile 8q x 4v (32 acc).
// W staged transposed [k][q] so the inner loop uses b128 LDS reads only.
// ---------------------------------------------------------------------------
#define K3_QT 128
#define K3_VT 64
#define K3_KT 32

__global__ __launch_bounds__(256, 2)
void k_attn_v(const float* __restrict__ Wm,
              const float* __restrict__ Vm,
              float* __restrict__ O)
{
    __shared__ float sWt[K3_KT][K3_QT + 4];   // [k][q], 32x132
    __shared__ float sV [K3_KT][K3_VT + 4];   // [k][v], 32x68

    const int t  = threadIdx.x;
    const int b  = blockIdx.z;
    const int qt = blockIdx.y * K3_QT;
    const int vt = blockIdx.x * K3_VT;
    const int qg = t >> 4;   // 0..15 -> 8 q rows
    const int vg = t & 15;   // 0..15 -> 4 v cols

    float acc[8][4];
#pragma unroll
    for (int r = 0; r < 8; ++r)
#pragma unroll
        for (int c = 0; c < 4; ++c) acc[r][c] = 0.f;

    const float* Wb = Wm + (size_t)b * NQ_ * NK_;
    const float* Vb = Vm + (size_t)b * NK_ * V_;

    for (int kt = 0; kt < NK_; kt += K3_KT) {
        __syncthreads();
        // stage W tile transposed: 128 rows x 32 k = 1024 f4, 4 per thread
#pragma unroll
        for (int j = 0; j < 4; ++j) {
            int idx = t + j * 256;
            int q = idx >> 3, c = idx & 7;
            float4 w4 = *(const float4*)(Wb + (size_t)(qt + q) * NK_ + kt + c*4);
            sWt[c*4+0][q] = w4.x; sWt[c*4+1][q] = w4.y;
            sWt[c*4+2][q] = w4.z; sWt[c*4+3][q] = w4.w;
        }
        // stage V tile: 32 rows x 64 v = 512 f4, 2 per thread
#pragma unroll
        for (int j = 0; j < 2; ++j) {
            int idx = t + j * 256;
            int row = idx >> 4, c = idx & 15;
            *(float4*)&sV[row][c*4] =
                *(const float4*)(Vb + (size_t)(kt + row) * V_ + vt + c*4);
        }
        __syncthreads();

#pragma unroll
        for (int k = 0; k < K3_KT; ++k) {
            float4 vv = *(const float4*)&sV[k][vg*4];
            float4 wlo = *(const float4*)&sWt[k][qg*8];
            float4 whi = *(const float4*)&sWt[k][qg*8 + 4];
            float wq[8];
            wq[0] = wlo.x; wq[1] = wlo.y; wq[2] = wlo.z; wq[3] = wlo.w;
            wq[4] = whi.x; wq[5] = whi.y; wq[6] = whi.z; wq[7] = whi.w;
#pragma unroll
            for (int r = 0; r < 8; ++r) {
                acc[r][0] = fmaf(wq[r], vv.x, acc[r][0]);
                acc[r][1] = fmaf(wq[r], vv.y, acc[r][1]);
                acc[r][2] = fmaf(wq[r], vv.z, acc[r][2]);
                acc[r][3] = fmaf(wq[r], vv.w, acc[r][3]);
            }
        }
    }

#pragma unroll
    for (int r = 0; r < 8; ++r) {
        float4 o;
        o.x = acc[r][0]; o.y = acc[r][1]; o.z = acc[r][2]; o.w = acc[r][3];
        *(float4*)(O + ((size_t)b * NQ_ + qt + qg*8 + r) * V_ + vt + vg*4) = o;
    }
}

// ---------------------------------------------------------------------------
extern "C" void kernel_launch(void* const* d_in, const int* in_sizes, int n_in,
                              void* d_out, int out_size, void* d_ws, size_t ws_size,
                              hipStream_t stream)
{
    const float* Q  = (const float*)d_in[0];
    const float* Kp = (const float*)d_in[1];
    const float* Vp = (const float*)d_in[2];

    float* O     = (float*)d_out;                       // (B, Nq, V)
    float* attnW = O + (size_t)BB * NQ_ * V_;           // (B, Nq, Nk)

    k_scores_softmax<<<dim3(NQ_ / K1_QT, BB), 256, 0, stream>>>(Q, Kp, attnW);
    k_attn_v<<<dim3(V_ / K3_VT, NQ_ / K3_QT, BB), 256, 0, stream>>>(attnW, Vp, O);
}

// Round 3
// 368.901 us; speedup vs baseline: 2.4439x; 2.4439x over previous
//
#include <hip/hip_runtime.h>
#include <math.h>

#define BB 8
#define NQ 2048
#define NK 2048
#define DD 64
#define VV 128
#define EPSF 1e-7f

typedef _Float16 half_t;
typedef half_t half8 __attribute__((ext_vector_type(8)));
typedef float  floatx4 __attribute__((ext_vector_type(4)));

// scores -> exp(score); all fp32 except xy which came from fp16 MFMA.
// dist = arccosh(1+tt) = log(1 + (tt + sqrt(tt*(tt+2))))
__device__ __forceinline__ float score_exp(float x2, float px, float y2, float py, float xy)
{
    float sq = fmaxf(x2 + y2 - 2.f * xy, 0.f);
    float dn = fmaxf(px * py, EPSF);
    float tt = fmaxf(2.f * sq * __builtin_amdgcn_rcpf(dn), EPSF);
    float u  = tt + __builtin_amdgcn_sqrtf(tt * (tt + 2.f));
    float d  = __logf(1.f + u);
    return __expf(-d * d);
}

__device__ __forceinline__ half8 cvt8(float4 a, float4 b)
{
    half8 h;
    h[0] = (half_t)a.x; h[1] = (half_t)a.y; h[2] = (half_t)a.z; h[3] = (half_t)a.w;
    h[4] = (half_t)b.x; h[5] = (half_t)b.y; h[6] = (half_t)b.z; h[7] = (half_t)b.w;
    return h;
}

// ---------------------------------------------------------------------------
// K1: scores + softmax via fp16 MFMA (16x16x32). Block = 256 thr = 4 waves,
// 64 q rows (wave w owns rows w*16..w*16+15), loops over all 2048 k cols.
// Phase 1 accumulates per-row exp-sums (registers + shfl), phase 2 recomputes
// and writes normalized fp32 weights once. x2/y2 computed fp32 from originals.
// ---------------------------------------------------------------------------
__global__ __launch_bounds__(256)
void k1_scores(const float* __restrict__ Q, const float* __restrict__ Kp,
               float* __restrict__ W)
{
    __shared__ half8 sB[8 * 64];          // frag-major K-tile: frag f=nt*2+ds, lane
    __shared__ float y2k[NK], pyk[NK];    // fp32 norms for ALL k rows
    __shared__ float x2q[64], pxq[64];

    const int t = threadIdx.x, w = t >> 6, lane = t & 63;
    const int n = lane & 15, quad = lane >> 4;
    const int b = blockIdx.y, qb = blockIdx.x * 64;

    const float* Kb = Kp + (size_t)b * NK * DD;
    const float* Qb = Q  + (size_t)b * NQ * DD;

    // fp32 y2/py for all K rows (block-local, no workspace)
#pragma unroll
    for (int j = 0; j < 8; ++j) {
        int row = t + j * 256;
        const float4* kr = (const float4*)(Kb + (size_t)row * DD);
        float s = 0.f;
#pragma unroll
        for (int i = 0; i < 16; ++i) {
            float4 v = kr[i];
            s = fmaf(v.x, v.x, s); s = fmaf(v.y, v.y, s);
            s = fmaf(v.z, v.z, s); s = fmaf(v.w, v.w, s);
        }
        y2k[row] = s; pyk[row] = 1.f - s;
    }
    if (t < 64) {
        const float4* qr = (const float4*)(Qb + (size_t)(qb + t) * DD);
        float s = 0.f;
#pragma unroll
        for (int i = 0; i < 16; ++i) {
            float4 v = qr[i];
            s = fmaf(v.x, v.x, s); s = fmaf(v.y, v.y, s);
            s = fmaf(v.z, v.z, s); s = fmaf(v.w, v.w, s);
        }
        x2q[t] = s; pxq[t] = 1.f - s;
    }
    __syncthreads();

    // A-frags: lane holds Q[qb + w*16 + (lane&15)][ds*32 + quad*8 + j]
    half8 af[2];
#pragma unroll
    for (int ds = 0; ds < 2; ++ds) {
        const float4* qp = (const float4*)(Qb + (size_t)(qb + w * 16 + n) * DD + ds * 32 + quad * 8);
        af[ds] = cvt8(qp[0], qp[1]);
    }
    // per-lane C-row constants: rows r = w*16 + quad*4 + reg
    float x2r[4], pxr[4];
#pragma unroll
    for (int r = 0; r < 4; ++r) {
        x2r[r] = x2q[w * 16 + quad * 4 + r];
        pxr[r] = pxq[w * 16 + quad * 4 + r];
    }

    auto stage = [&](int kt) {
        __syncthreads();
#pragma unroll
        for (int i = 0; i < 2; ++i) {
            int s = t + i * 256, f = s >> 6, l = s & 63;
            int krow = kt + (f >> 1) * 16 + (l & 15);
            int d = (f & 1) * 32 + (l >> 4) * 8;
            const float4* kp = (const float4*)(Kb + (size_t)krow * DD + d);
            sB[s] = cvt8(kp[0], kp[1]);
        }
        __syncthreads();
    };

    // ---- phase 1: row exp-sums
    float lsum[4] = {0.f, 0.f, 0.f, 0.f};
    for (int kt = 0; kt < NK; kt += 64) {
        stage(kt);
        floatx4 acc[4] = {};
#pragma unroll
        for (int nt = 0; nt < 4; ++nt)
#pragma unroll
            for (int ds = 0; ds < 2; ++ds)
                acc[nt] = __builtin_amdgcn_mfma_f32_16x16x32_f16(
                    af[ds], sB[(nt * 2 + ds) * 64 + lane], acc[nt], 0, 0, 0);
#pragma unroll
        for (int nt = 0; nt < 4; ++nt) {
            int col = kt + nt * 16 + n;
            float y2 = y2k[col], py = pyk[col];
#pragma unroll
            for (int r = 0; r < 4; ++r)
                lsum[r] += score_exp(x2r[r], pxr[r], y2, py, acc[nt][r]);
        }
    }
#pragma unroll
    for (int off = 1; off < 16; off <<= 1)
#pragma unroll
        for (int r = 0; r < 4; ++r) lsum[r] += __shfl_xor(lsum[r], off);
    float rl[4];
#pragma unroll
    for (int r = 0; r < 4; ++r) rl[r] = __builtin_amdgcn_rcpf(lsum[r]);

    // ---- phase 2: recompute, normalize, write fp32 weights
    float* Wb = W + (size_t)b * NQ * NK + (size_t)qb * NK;
    for (int kt = 0; kt < NK; kt += 64) {
        stage(kt);
        floatx4 acc[4] = {};
#pragma unroll
        for (int nt = 0; nt < 4; ++nt)
#pragma unroll
            for (int ds = 0; ds < 2; ++ds)
                acc[nt] = __builtin_amdgcn_mfma_f32_16x16x32_f16(
                    af[ds], sB[(nt * 2 + ds) * 64 + lane], acc[nt], 0, 0, 0);
#pragma unroll
        for (int nt = 0; nt < 4; ++nt) {
            int col = kt + nt * 16 + n;
            float y2 = y2k[col], py = pyk[col];
#pragma unroll
            for (int r = 0; r < 4; ++r) {
                float e = score_exp(x2r[r], pxr[r], y2, py, acc[nt][r]) * rl[r];
                Wb[(size_t)(w * 16 + quad * 4 + r) * NK + col] = e;
            }
        }
    }
}

// ---------------------------------------------------------------------------
// K3: O = W @ V via fp16 MFMA. Block = 256 thr, 64 q rows x all 128 v cols.
// A-frags (W) loaded direct from global + cvt; V-tile (32k x 128v) staged to
// LDS frag-major with coalesced strided b32 loads (4 rows x 64B per instr).
// ---------------------------------------------------------------------------
__global__ __launch_bounds__(256)
void k3_pv(const float* __restrict__ W, const float* __restrict__ V,
           float* __restrict__ O)
{
    __shared__ half8 sV[8 * 64];          // frag nt (8), lane

    const int t = threadIdx.x, w = t >> 6, lane = t & 63;
    const int n = lane & 15, quad = lane >> 4;
    const int b = blockIdx.y, qb = blockIdx.x * 64;

    const float* Wb = W + (size_t)b * NQ * NK;
    const float* Vb = V + (size_t)b * NK * VV;

    floatx4 acc[8] = {};

    for (int kt = 0; kt < NK; kt += 32) {
        __syncthreads();
#pragma unroll
        for (int i = 0; i < 2; ++i) {
            int s = t + i * 256, nt = s >> 6, l = s & 63;
            const float* vp = Vb + (size_t)(kt + (l >> 4) * 8) * VV + nt * 16 + (l & 15);
            half8 h;
#pragma unroll
            for (int j = 0; j < 8; ++j) h[j] = (half_t)vp[(size_t)j * VV];
            sV[s] = h;
        }
        __syncthreads();

        // A-frag: lane holds W[qb + w*16 + (lane&15)][kt + quad*8 + j]
        const float4* wp = (const float4*)(Wb + (size_t)(qb + w * 16 + n) * NK + kt + quad * 8);
        half8 aw = cvt8(wp[0], wp[1]);
#pragma unroll
        for (int nt = 0; nt < 8; ++nt)
            acc[nt] = __builtin_amdgcn_mfma_f32_16x16x32_f16(
                aw, sV[nt * 64 + lane], acc[nt], 0, 0, 0);
    }

    float* Ob = O + (size_t)b * NQ * VV;
#pragma unroll
    for (int nt = 0; nt < 8; ++nt)
#pragma unroll
        for (int r = 0; r < 4; ++r)
            Ob[(size_t)(qb + w * 16 + quad * 4 + r) * VV + nt * 16 + n] = acc[nt][r];
}

// ---------------------------------------------------------------------------
extern "C" void kernel_launch(void* const* d_in, const int* in_sizes, int n_in,
                              void* d_out, int out_size, void* d_ws, size_t ws_size,
                              hipStream_t stream)
{
    const float* Q  = (const float*)d_in[0];
    const float* Kp = (const float*)d_in[1];
    const float* Vp = (const float*)d_in[2];

    float* O     = (float*)d_out;                 // (B, Nq, V)
    float* attnW = O + (size_t)BB * NQ * VV;      // (B, Nq, Nk)

    k1_scores<<<dim3(NQ / 64, BB), 256, 0, stream>>>(Q, Kp, attnW);
    k3_pv    <<<dim3(NQ / 64, BB), 256, 0, stream>>>(attnW, Vp, O);
}

// Round 6
// 345.548 us; speedup vs baseline: 2.6091x; 1.0676x over previous
//
#include <hip/hip_runtime.h>
#include <math.h>

#define BB 8
#define NQ 2048
#define NK 2048
#define DD 64
#define VV 128
#define EPSF 1e-7f

typedef _Float16 half_t;
typedef half_t half8 __attribute__((ext_vector_type(8)));
typedef float  floatx4 __attribute__((ext_vector_type(4)));

// exp(-arccosh(1+tt)^2); tt from fp32 norms + fp16-MFMA cross term.
// arccosh(1+tt) = ln(1+u), u = tt + sqrt(tt*(tt+2))   [R3-proven intrinsics]
__device__ __forceinline__ float score_exp(float x2, float px, float y2, float py, float xy)
{
    float sq = fmaxf(x2 + y2 - 2.f * xy, 0.f);
    float dn = fmaxf(px * py, EPSF);
    float tt = fmaxf(2.f * sq * __builtin_amdgcn_rcpf(dn), EPSF);
    float u  = tt + __builtin_amdgcn_sqrtf(fmaf(tt, tt, tt + tt));
    float d  = __logf(1.f + u);
    return __expf(-d * d);
}

__device__ __forceinline__ half8 cvt8(float4 a, float4 b)
{
    half8 h;
    h[0] = (half_t)a.x; h[1] = (half_t)a.y; h[2] = (half_t)a.z; h[3] = (half_t)a.w;
    h[4] = (half_t)b.x; h[5] = (half_t)b.y; h[6] = (half_t)b.z; h[7] = (half_t)b.w;
    return h;
}

// ---------------------------------------------------------------------------
// K1 (one pass): E = exp(score), unnormalized -> global (W region of d_out).
// Block = 256 thr = 4 waves = (q-half, k-half); 32 q rows; grid 512 blocks
// (2 blocks/CU). Each wave sweeps its 1024 k cols with fp16 MFMA.
// ---------------------------------------------------------------------------
__global__ __launch_bounds__(256)
void k1_scores(const float* __restrict__ Q, const float* __restrict__ Kp,
               float* __restrict__ E)
{
    __shared__ half8 sB[2][8 * 64];       // [k-half][frag*64+lane]
    __shared__ float y2k[NK], pyk[NK];
    __shared__ float x2q[32], pxq[32];

    const int t = threadIdx.x, w = t >> 6, lane = t & 63;
    const int n = lane & 15, quad = lane >> 4;
    const int qh = w & 1, kh = w >> 1;
    const int b = blockIdx.y, qb = blockIdx.x * 32;

    const float* Kb = Kp + (size_t)b * NK * DD;
    const float* Qb = Q  + (size_t)b * NQ * DD;

    // fp32 norms: all 2048 K rows (8/thread) + this block's 32 Q rows
#pragma unroll
    for (int j = 0; j < 8; ++j) {
        int row = t + j * 256;
        const float4* kr = (const float4*)(Kb + (size_t)row * DD);
        float s = 0.f;
#pragma unroll
        for (int i = 0; i < 16; ++i) {
            float4 v = kr[i];
            s = fmaf(v.x,v.x,s); s = fmaf(v.y,v.y,s);
            s = fmaf(v.z,v.z,s); s = fmaf(v.w,v.w,s);
        }
        y2k[row] = s; pyk[row] = 1.f - s;
    }
    if (t < 32) {
        const float4* qr = (const float4*)(Qb + (size_t)(qb + t) * DD);
        float s = 0.f;
#pragma unroll
        for (int i = 0; i < 16; ++i) {
            float4 v = qr[i];
            s = fmaf(v.x,v.x,s); s = fmaf(v.y,v.y,s);
            s = fmaf(v.z,v.z,s); s = fmaf(v.w,v.w,s);
        }
        x2q[t] = s; pxq[t] = 1.f - s;
    }
    __syncthreads();

    // A-frags: lane holds Q[qb + qh*16 + n][ds*32 + quad*8 + j]
    half8 af[2];
#pragma unroll
    for (int ds = 0; ds < 2; ++ds) {
        const float4* qp = (const float4*)(Qb + (size_t)(qb + qh*16 + n) * DD + ds*32 + quad*8);
        af[ds] = cvt8(qp[0], qp[1]);
    }
    float x2r[4], pxr[4];
#pragma unroll
    for (int r = 0; r < 4; ++r) {
        x2r[r] = x2q[qh*16 + quad*4 + r];
        pxr[r] = pxq[qh*16 + quad*4 + r];
    }

    float* Eb = E + (size_t)b * NQ * NK;
    const int kbase = kh * 1024;

    for (int kt0 = 0; kt0 < 1024; kt0 += 64) {
        __syncthreads();
        // stage both 64-col k-halves: 1024 half8, 4/thread
#pragma unroll
        for (int i = 0; i < 4; ++i) {
            int s = t + i * 256;
            int h = s >> 9, f = (s >> 6) & 7, l = s & 63;
            int krow = h * 1024 + kt0 + (f >> 1) * 16 + (l & 15);
            int dcol = (f & 1) * 32 + (l >> 4) * 8;
            const float4* kp = (const float4*)(Kb + (size_t)krow * DD + dcol);
            sB[h][f * 64 + l] = cvt8(kp[0], kp[1]);
        }
        __syncthreads();

        floatx4 acc[4] = {};
#pragma unroll
        for (int nt = 0; nt < 4; ++nt)
#pragma unroll
            for (int ds = 0; ds < 2; ++ds)
                acc[nt] = __builtin_amdgcn_mfma_f32_16x16x32_f16(
                    af[ds], sB[kh][(nt * 2 + ds) * 64 + lane], acc[nt], 0, 0, 0);

#pragma unroll
        for (int nt = 0; nt < 4; ++nt) {
            int col = kbase + kt0 + nt * 16 + n;
            float y2 = y2k[col], py = pyk[col];
#pragma unroll
            for (int r = 0; r < 4; ++r)
                Eb[(size_t)(qb + qh * 16 + quad * 4 + r) * NK + col]
                    = score_exp(x2r[r], pxr[r], y2, py, acc[nt][r]);
        }
    }
}

// ---------------------------------------------------------------------------
// K3: phase 0 computes row sums of E (block owns rows qb..qb+31, ALL v cols,
// so each E row belongs to exactly one block -> no ws needed). Main loop:
// in-place write-back W = E*rl at the addresses just read, normalized fp16
// A-frags -> O = MFMA directly (no epilogue scale).
// ---------------------------------------------------------------------------
__global__ __launch_bounds__(256)
void k3_pv(float* __restrict__ EW, const float* __restrict__ V,
           float* __restrict__ O)
{
    __shared__ half8 sEf[4 * 64];     // [(wq*2+ds)*64 + lane]
    __shared__ half8 sV [16 * 64];    // [(fnt*2+dsv)*64 + lane]
    __shared__ float rsum[32];

    const int t = threadIdx.x, w = t >> 6, lane = t & 63;
    const int n = lane & 15, quad = lane >> 4;
    const int wq = w & 1, wv = w >> 1;
    const int b = blockIdx.y, qb = blockIdx.x * 32;

    float* Eb = EW + (size_t)b * NQ * NK;
    const float* Vb = V + (size_t)b * NK * VV;

    // ---- phase 0: row sums (8 threads per row, coalesced float4)
    const int srow = t >> 3, scg = t & 7;
    const float* Er0 = Eb + (size_t)(qb + srow) * NK;
    float s = 0.f;
#pragma unroll 4
    for (int j = 0; j < 64; ++j) {
        float4 e = *(const float4*)(Er0 + scg * 4 + j * 32);
        s += (e.x + e.y) + (e.z + e.w);
    }
#pragma unroll
    for (int off = 1; off < 8; off <<= 1) s += __shfl_xor(s, off);
    if ((lane & 7) == 0) rsum[t >> 3] = s;
    __syncthreads();

    // ---- main loop
    const int erow = t >> 3;          // staging row (same as srow)
    const int ecg  = (t & 7) * 8;     // 8-col group within 64-wide tile
    const float rl_my = __builtin_amdgcn_rcpf(rsum[erow]);
    float* Er = Eb + (size_t)(qb + erow) * NK;
    const int eslot = ((erow >> 4) * 2 + (ecg >> 5)) * 64 + ((ecg & 31) >> 3) * 16 + (erow & 15);

    floatx4 acc[4] = {};

    for (int kt = 0; kt < NK; kt += 64) {
        __syncthreads();
        // E tile: coalesced read -> normalize -> write-back W -> fp16 frag LDS
        float4 e0 = *(const float4*)(Er + kt + ecg);
        float4 e1 = *(const float4*)(Er + kt + ecg + 4);
        e0.x *= rl_my; e0.y *= rl_my; e0.z *= rl_my; e0.w *= rl_my;
        e1.x *= rl_my; e1.y *= rl_my; e1.z *= rl_my; e1.w *= rl_my;
        *(float4*)(Er + kt + ecg)     = e0;
        *(float4*)(Er + kt + ecg + 4) = e1;
        sEf[eslot] = cvt8(e0, e1);
        // V tile 64k x 128v, frag-major (strided b32 loads, L2/L3-hot)
#pragma unroll
        for (int i = 0; i < 4; ++i) {
            int sidx = t + i * 256, f = sidx >> 6, l = sidx & 63;
            const float* vp = Vb + (size_t)(kt + (f & 1) * 32 + (l >> 4) * 8) * VV
                                 + (f >> 1) * 16 + (l & 15);
            half8 h;
#pragma unroll
            for (int j = 0; j < 8; ++j) h[j] = (half_t)vp[j * VV];
            sV[f * 64 + l] = h;
        }
        __syncthreads();

        half8 a0 = sEf[(wq * 2 + 0) * 64 + lane];
        half8 a1 = sEf[(wq * 2 + 1) * 64 + lane];
#pragma unroll
        for (int nt = 0; nt < 4; ++nt) {
            int fnt = wv * 4 + nt;
            acc[nt] = __builtin_amdgcn_mfma_f32_16x16x32_f16(
                a0, sV[(fnt * 2 + 0) * 64 + lane], acc[nt], 0, 0, 0);
            acc[nt] = __builtin_amdgcn_mfma_f32_16x16x32_f16(
                a1, sV[(fnt * 2 + 1) * 64 + lane], acc[nt], 0, 0, 0);
        }
    }

    // A-frags were pre-normalized -> acc IS the output
    float* Ob = O + (size_t)b * NQ * VV;
#pragma unroll
    for (int nt = 0; nt < 4; ++nt)
#pragma unroll
        for (int r = 0; r < 4; ++r)
            Ob[(size_t)(qb + wq * 16 + quad * 4 + r) * VV + wv * 64 + nt * 16 + n]
                = acc[nt][r];
}

// ---------------------------------------------------------------------------
extern "C" void kernel_launch(void* const* d_in, const int* in_sizes, int n_in,
                              void* d_out, int out_size, void* d_ws, size_t ws_size,
                              hipStream_t stream)
{
    const float* Q  = (const float*)d_in[0];
    const float* Kp = (const float*)d_in[1];
    const float* Vp = (const float*)d_in[2];

    float* O     = (float*)d_out;                 // (B, Nq, V)
    float* attnW = O + (size_t)BB * NQ * VV;      // (B, Nq, Nk): E, then W in-place

    k1_scores<<<dim3(NQ / 32, BB), 256, 0, stream>>>(Q, Kp, attnW);
    k3_pv    <<<dim3(NQ / 32, BB), 256, 0, stream>>>(attnW, Vp, O);
}